// Round 1
// 429.473 us; speedup vs baseline: 1.0413x; 1.0413x over previous
//
#include <hip/hip_runtime.h>

// Problem constants
#define NB 2
#define NN 160
#define NPAIR (NN*NN)          // 25600
#define OUT_PAIRS_OFF 307200   // 3 * NB*NPAIR*2 fp32 elements before emb_pairs

// emb_pairs region: 19,660,800 float4 chunks (314.6 MB)
#define TOTAL_CHUNKS 19660800
// proj scratch (6*320*512 fp32 = 983,040 floats = 245,760 chunks) lives in the
// TAIL of the emb_pairs region now; written by K1, read by K2 heads blocks,
// overwritten by K3 last.
#define TAIL_CHUNKS 245760
#define TAIL_START (TOTAL_CHUNKS - TAIL_CHUNKS)        // 19,415,040
#define PROJ_SCRATCH_OFF (OUT_PAIRS_OFF + 4*TAIL_START) // float offset 77,967,360

// pairs slice split: K1 covers [0, S1), K2 covers [S1, TAIL_START), K3 the tail
#define K1_PAIR_BLOCKS 42240
#define S1_CHUNKS (K1_PAIR_BLOCKS*256)                 // 10,813,440 (~55%)
#define K2_PAIR_BLOCKS 33600                           // (TAIL_START - S1)/256

// ---------------------------------------------------------------------------
// pairs chunk writer (identical math to the verified pairs_kernel)
// ---------------------------------------------------------------------------
__device__ __forceinline__ void pairs_chunk(
    const float* __restrict__ geo, const float* __restrict__ app,
    const float* __restrict__ con, float4* __restrict__ outp, int idx)
{
    const int row = idx / 384;
    const int c   = idx - row * 384;
    const int b   = row / 25600;
    const int rem = row - b * 25600;
    const int i   = rem / 160;
    const int j   = rem - i * 160;

    int cc = c, pt = j;                 // first half = emb[b, j]
    if (c >= 192) { pt = i; cc = c - 192; }
    const int m   = cc >> 6;            // 64 chunks per modality (256 floats)
    const int off = cc & 63;
    const float* src = ((m == 0) ? geo : (m == 1) ? app : con)
                       + ((size_t)(b * 160 + pt)) * 256 + off * 4;

    outp[idx] = *(const float4*)src;
}

// ---------------------------------------------------------------------------
// K1: blocks [0,240) = factorized projections (fp32 VALU GEMM, verified body):
//   proj[(t*2+s)*320 + p][f] = sum_{c<768} emb[p][c] * W1_t[s*768+c][f] (+b1)
// blocks [240, 240+K1_PAIR_BLOCKS) = pairs chunks [0, S1) — saturate HBM
// writes while the GEMM (compute-bound) runs on the first ~240 CUs.
// ---------------------------------------------------------------------------
__global__ __launch_bounds__(256) void k1_proj_pairs(
    const float* __restrict__ geo, const float* __restrict__ app,
    const float* __restrict__ con,
    const float* __restrict__ w1c, const float* __restrict__ w1r,
    const float* __restrict__ w1l,
    const float* __restrict__ b1c, const float* __restrict__ b1r,
    const float* __restrict__ b1l,
    float* __restrict__ proj, float4* __restrict__ outp)
{
    const int tid = threadIdx.x;
    const int bid = blockIdx.x;

    if (bid >= 240) {
        pairs_chunk(geo, app, con, outp, (bid - 240) * 256 + tid);
        return;
    }

    __shared__ float As[64][17];
    __shared__ float Bs[16][68];

    const int m0 = (bid % 5) * 64;
    const int n0 = (bid / 5) * 64;
    const int t  = n0 >> 10;
    const int s  = (n0 >> 9) & 1;
    const int f0 = n0 & 511;

    const float* w1 = (t == 0) ? w1c : ((t == 1) ? w1r : w1l);
    const float* b1 = (t == 0) ? b1c : ((t == 1) ? b1r : b1l);

    const int ty = tid >> 4, tx = tid & 15;
    const int ar = tid >> 2, ac = (tid & 3) * 4;
    const int bk = tid >> 4, bn = (tid & 15) * 4;

    float acc[4][4] = {};

    for (int k0 = 0; k0 < 768; k0 += 16) {
        {
            const int c = k0 + ac;
            const int m = c >> 8, off = c & 255;
            const float* src = ((m == 0) ? geo : (m == 1) ? app : con)
                               + (size_t)(m0 + ar) * 256 + off;
            const float4 v = *(const float4*)src;
            As[ar][ac + 0] = v.x; As[ar][ac + 1] = v.y;
            As[ar][ac + 2] = v.z; As[ar][ac + 3] = v.w;
        }
        {
            const float4 v = *(const float4*)(
                w1 + (size_t)(s * 768 + k0 + bk) * 512 + f0 + bn);
            Bs[bk][bn + 0] = v.x; Bs[bk][bn + 1] = v.y;
            Bs[bk][bn + 2] = v.z; Bs[bk][bn + 3] = v.w;
        }
        __syncthreads();

        #pragma unroll
        for (int k = 0; k < 16; ++k) {
            const float4 b = *(const float4*)&Bs[k][tx * 4];
            const float a0 = As[ty * 4 + 0][k];
            const float a1 = As[ty * 4 + 1][k];
            const float a2 = As[ty * 4 + 2][k];
            const float a3 = As[ty * 4 + 3][k];
            acc[0][0] += a0 * b.x; acc[0][1] += a0 * b.y;
            acc[0][2] += a0 * b.z; acc[0][3] += a0 * b.w;
            acc[1][0] += a1 * b.x; acc[1][1] += a1 * b.y;
            acc[1][2] += a1 * b.z; acc[1][3] += a1 * b.w;
            acc[2][0] += a2 * b.x; acc[2][1] += a2 * b.y;
            acc[2][2] += a2 * b.z; acc[2][3] += a2 * b.w;
            acc[3][0] += a3 * b.x; acc[3][1] += a3 * b.y;
            acc[3][2] += a3 * b.z; acc[3][3] += a3 * b.w;
        }
        __syncthreads();
    }

    float4 bias = {0.f, 0.f, 0.f, 0.f};
    if (s == 0) bias = *(const float4*)&b1[f0 + tx * 4];

    #pragma unroll
    for (int r = 0; r < 4; ++r) {
        float4 o;
        o.x = acc[r][0] + bias.x; o.y = acc[r][1] + bias.y;
        o.z = acc[r][2] + bias.z; o.w = acc[r][3] + bias.w;
        *(float4*)&proj[(size_t)((t * 2 + s) * 320 + m0 + ty * 4 + r) * 512
                        + f0 + tx * 4] = o;
    }
}

// ---------------------------------------------------------------------------
// K2: blocks [0,200) = heads, restructured to 256-thread blocks handling a
// 16x16 pair tile (same per-pair FMA order as the verified 8x8 version ->
// bitwise-identical output; 1/4 the proj staging traffic per pair).
// blocks [200, 200+K2_PAIR_BLOCKS) = pairs chunks [S1, TAIL_START) — keep HBM
// writes saturated while heads (LDS-bound) runs.
// ---------------------------------------------------------------------------
__global__ __launch_bounds__(256) void k2_heads_pairs(
    const float* __restrict__ geo, const float* __restrict__ app,
    const float* __restrict__ con,
    const float* __restrict__ proj,
    const float* __restrict__ w2c, const float* __restrict__ b2c,
    const float* __restrict__ w2r, const float* __restrict__ b2r,
    const float* __restrict__ w2l, const float* __restrict__ b2l,
    float* __restrict__ out, float4* __restrict__ outp)
{
    const int tid = threadIdx.x;
    const int bid = blockIdx.x;

    if (bid >= 200) {
        pairs_chunk(geo, app, con, outp,
                    S1_CHUNKS + (bid - 200) * 256 + tid);
        return;
    }

    __shared__ float P1s[16][516];
    __shared__ float P2s[16][516];
    __shared__ float w2s[1024];
    __shared__ float b2s[2];

    const int b   = bid / 100;           // 10x10 tiles of 16x16 per batch
    const int rem = bid - b * 100;
    const int it  = rem / 10;
    const int jt  = rem - it * 10;
    const int i0 = it * 16, j0 = jt * 16;
    const int ii = tid >> 4, jj = tid & 15;

    #pragma unroll
    for (int t = 0; t < 3; ++t) {
        const float* w2 = (t == 0) ? w2c : ((t == 1) ? w2r : w2l);
        const float* b2 = (t == 0) ? b2c : ((t == 1) ? b2r : b2l);

        // stage P1 (j rows) and P2 (i rows): 2 tiles * 16 rows * 128 float4
        for (int u = tid; u < 4096; u += 256) {
            const int tile = u >> 11;
            const int r    = (u >> 7) & 15;
            const int f4   = u & 127;
            const int p    = b * 160 + (tile ? (i0 + r) : (j0 + r));
            const float4 v = *(const float4*)(
                proj + ((size_t)((t * 2 + tile) * 320 + p)) * 512 + f4 * 4);
            float* dst = tile ? &P2s[r][f4 * 4] : &P1s[r][f4 * 4];
            *(float4*)dst = v;
        }
        if (tid < 256) // 256 float4 = full W2 (512x2)
            *(float4*)&w2s[tid * 4] = *(const float4*)(w2 + tid * 4);
        if (tid < 2) b2s[tid] = b2[tid];
        __syncthreads();

        float a0 = b2s[0], a1 = b2s[1];
        for (int f = 0; f < 512; f += 4) {
            const float4 p1 = *(const float4*)&P1s[jj][f];
            const float4 p2 = *(const float4*)&P2s[ii][f];
            const float4 wA = *(const float4*)&w2s[f * 2];      // f, f+1
            const float4 wB = *(const float4*)&w2s[f * 2 + 4];  // f+2, f+3
            const float h0 = fmaxf(p1.x + p2.x, 0.f);
            const float h1 = fmaxf(p1.y + p2.y, 0.f);
            const float h2 = fmaxf(p1.z + p2.z, 0.f);
            const float h3 = fmaxf(p1.w + p2.w, 0.f);
            a0 += h0 * wA.x + h1 * wA.z + h2 * wB.x + h3 * wB.z;
            a1 += h0 * wA.y + h1 * wA.w + h2 * wB.y + h3 * wB.w;
        }

        const float mx = fmaxf(a0, a1);
        const float e0 = __expf(a0 - mx);
        const float e1 = __expf(a1 - mx);
        const float rs = 1.f / (e0 + e1);

        const int pr = b * 25600 + (i0 + ii) * 160 + (j0 + jj);
        float2 o; o.x = e0 * rs; o.y = e1 * rs;
        ((float2*)out)[t * 51200 + pr] = o;
        __syncthreads();
    }
}

// ---------------------------------------------------------------------------
// K3: tail pairs chunks [TAIL_START, TOTAL_CHUNKS) — overwrites the proj
// scratch AFTER heads has consumed it. 3.93 MB, ~1.5 us.
// ---------------------------------------------------------------------------
__global__ __launch_bounds__(256) void k3_pairs_tail(
    const float* __restrict__ geo, const float* __restrict__ app,
    const float* __restrict__ con, float4* __restrict__ outp)
{
    pairs_chunk(geo, app, con, outp,
                TAIL_START + blockIdx.x * 256 + threadIdx.x);
}

extern "C" void kernel_launch(void* const* d_in, const int* in_sizes, int n_in,
                              void* d_out, int out_size, void* d_ws, size_t ws_size,
                              hipStream_t stream)
{
    const float* geo = (const float*)d_in[0];
    const float* app = (const float*)d_in[1];
    const float* con = (const float*)d_in[2];
    const float* w1c = (const float*)d_in[3];
    const float* b1c = (const float*)d_in[4];
    const float* w2c = (const float*)d_in[5];
    const float* b2c = (const float*)d_in[6];
    const float* w1r = (const float*)d_in[7];
    const float* b1r = (const float*)d_in[8];
    const float* w2r = (const float*)d_in[9];
    const float* b2r = (const float*)d_in[10];
    const float* w1l = (const float*)d_in[11];
    const float* b1l = (const float*)d_in[12];
    const float* w2l = (const float*)d_in[13];
    const float* b2l = (const float*)d_in[14];

    float* out = (float*)d_out;

    // proj scratch now at the TAIL of the emb_pairs region (last 3.93 MB);
    // K1/K2 pairs slices never touch it, K3 overwrites it last. No d_ws use.
    float* proj = out + PROJ_SCRATCH_OFF;
    float4* outp = (float4*)(out + OUT_PAIRS_OFF);

    // 1) proj GEMM (240 blocks, dispatched first) + pairs slice A (55%)
    k1_proj_pairs<<<240 + K1_PAIR_BLOCKS, 256, 0, stream>>>(
        geo, app, con, w1c, w1r, w1l, b1c, b1r, b1l, proj, outp);

    // 2) heads (200 blocks of 16x16 tiles) + pairs slice B (45% minus tail)
    k2_heads_pairs<<<200 + K2_PAIR_BLOCKS, 256, 0, stream>>>(
        geo, app, con, proj, w2c, b2c, w2r, b2r, w2l, b2l, out, outp);

    // 3) tail (overwrites proj scratch)
    k3_pairs_tail<<<960, 256, 0, stream>>>(geo, app, con, outp);
}

// Round 2
// 418.487 us; speedup vs baseline: 1.0687x; 1.0263x over previous
//
#include <hip/hip_runtime.h>

// Problem constants
#define NB 2
#define NN 160
#define NPAIR (NN*NN)          // 25600
#define OUT_PAIRS_OFF 307200   // 3 * NB*NPAIR*2 fp32 elements before emb_pairs

// emb_pairs region: 19,660,800 float4 chunks (314.6 MB)
#define TOTAL_CHUNKS 19660800
// proj scratch = 6*320*512 fp32 = 3,932,160 B. Preferred home: d_ws.
// Fallback home (ws too small): TAIL of the emb_pairs region, overwritten
// by K3 after heads has consumed it (the round-1 verified scheme).
#define PROJ_BYTES 3932160
#define TAIL_CHUNKS 245760
#define TAIL_START (TOTAL_CHUNKS - TAIL_CHUNKS)         // 19,415,040
#define PROJ_SCRATCH_OFF (OUT_PAIRS_OFF + 4*TAIL_START) // float offset

// pairs slice split: K1 covers [0, S1), K2 covers [S1, end)
#define K1_PAIR_BLOCKS 42240
#define S1_CHUNKS (K1_PAIR_BLOCKS*256)                  // 10,813,440 (~55%)
#define K2_PAIR_BLOCKS_WS   34560                       // to TOTAL_CHUNKS
#define K2_PAIR_BLOCKS_TAIL 33600                       // to TAIL_START

// ---------------------------------------------------------------------------
// pairs chunk writer (identical math to the verified pairs_kernel)
// ---------------------------------------------------------------------------
__device__ __forceinline__ void pairs_chunk(
    const float* __restrict__ geo, const float* __restrict__ app,
    const float* __restrict__ con, float4* __restrict__ outp, int idx)
{
    const int row = idx / 384;
    const int c   = idx - row * 384;
    const int b   = row / 25600;
    const int rem = row - b * 25600;
    const int i   = rem / 160;
    const int j   = rem - i * 160;

    int cc = c, pt = j;                 // first half = emb[b, j]
    if (c >= 192) { pt = i; cc = c - 192; }
    const int m   = cc >> 6;            // 64 chunks per modality (256 floats)
    const int off = cc & 63;
    const float* src = ((m == 0) ? geo : (m == 1) ? app : con)
                       + ((size_t)(b * 160 + pt)) * 256 + off * 4;

    outp[idx] = *(const float4*)src;
}

// ---------------------------------------------------------------------------
// K1: blocks [0,240) = factorized projections (fp32 VALU GEMM):
//   proj[(t*2+s)*320 + p][f] = sum_{c<768} emb[p][c] * W1_t[s*768+c][f] (+b1)
// A tile now stored TRANSPOSED in LDS (Ast[k][m], pad 76): the k-loop reads
// A as one ds_read_b128 instead of 4 scalar ds_read_b32 -> VALU-bound loop.
// Same FMA order per output element (bitwise-identical results).
// blocks [240, ...) = pairs chunks [0, S1) — keep HBM writes saturated.
// ---------------------------------------------------------------------------
__global__ __launch_bounds__(256) void k1_proj_pairs(
    const float* __restrict__ geo, const float* __restrict__ app,
    const float* __restrict__ con,
    const float* __restrict__ w1c, const float* __restrict__ w1r,
    const float* __restrict__ w1l,
    const float* __restrict__ b1c, const float* __restrict__ b1r,
    const float* __restrict__ b1l,
    float* __restrict__ proj, float4* __restrict__ outp)
{
    const int tid = threadIdx.x;
    const int bid = blockIdx.x;

    if (bid >= 240) {
        pairs_chunk(geo, app, con, outp, (bid - 240) * 256 + tid);
        return;
    }

    // Ast: transposed A tile, [k][m]; pad 76 => row stride 304 B (16B-aligned
    // b128 reads at &Ast[k][ty*4]) and 2-way-free staging write banks.
    __shared__ float Ast[16][76];
    __shared__ float Bs[16][68];

    const int m0 = (bid % 5) * 64;
    const int n0 = (bid / 5) * 64;
    const int t  = n0 >> 10;
    const int s  = (n0 >> 9) & 1;
    const int f0 = n0 & 511;

    const float* w1 = (t == 0) ? w1c : ((t == 1) ? w1r : w1l);
    const float* b1 = (t == 0) ? b1c : ((t == 1) ? b1r : b1l);

    const int ty = tid >> 4, tx = tid & 15;
    const int ar = tid >> 2, ac = (tid & 3) * 4;
    const int bk = tid >> 4, bn = (tid & 15) * 4;

    float acc[4][4] = {};

    for (int k0 = 0; k0 < 768; k0 += 16) {
        {
            const int c = k0 + ac;
            const int m = c >> 8, off = c & 255;
            const float* src = ((m == 0) ? geo : (m == 1) ? app : con)
                               + (size_t)(m0 + ar) * 256 + off;
            const float4 v = *(const float4*)src;
            Ast[ac + 0][ar] = v.x; Ast[ac + 1][ar] = v.y;
            Ast[ac + 2][ar] = v.z; Ast[ac + 3][ar] = v.w;
        }
        {
            const float4 v = *(const float4*)(
                w1 + (size_t)(s * 768 + k0 + bk) * 512 + f0 + bn);
            Bs[bk][bn + 0] = v.x; Bs[bk][bn + 1] = v.y;
            Bs[bk][bn + 2] = v.z; Bs[bk][bn + 3] = v.w;
        }
        __syncthreads();

        #pragma unroll
        for (int k = 0; k < 16; ++k) {
            const float4 b = *(const float4*)&Bs[k][tx * 4];
            const float4 a = *(const float4*)&Ast[k][ty * 4];
            acc[0][0] += a.x * b.x; acc[0][1] += a.x * b.y;
            acc[0][2] += a.x * b.z; acc[0][3] += a.x * b.w;
            acc[1][0] += a.y * b.x; acc[1][1] += a.y * b.y;
            acc[1][2] += a.y * b.z; acc[1][3] += a.y * b.w;
            acc[2][0] += a.z * b.x; acc[2][1] += a.z * b.y;
            acc[2][2] += a.z * b.z; acc[2][3] += a.z * b.w;
            acc[3][0] += a.w * b.x; acc[3][1] += a.w * b.y;
            acc[3][2] += a.w * b.z; acc[3][3] += a.w * b.w;
        }
        __syncthreads();
    }

    float4 bias = {0.f, 0.f, 0.f, 0.f};
    if (s == 0) bias = *(const float4*)&b1[f0 + tx * 4];

    #pragma unroll
    for (int r = 0; r < 4; ++r) {
        float4 o;
        o.x = acc[r][0] + bias.x; o.y = acc[r][1] + bias.y;
        o.z = acc[r][2] + bias.z; o.w = acc[r][3] + bias.w;
        *(float4*)&proj[(size_t)((t * 2 + s) * 320 + m0 + ty * 4 + r) * 512
                        + f0 + tx * 4] = o;
    }
}

// ---------------------------------------------------------------------------
// K2: blocks [0,200) = heads (16x16 pair tile, 256 threads; per-pair FMA
// order identical to the verified version). blocks [200, ...) = pairs chunks
// [S1, S1 + nPairBlocks*256).
// ---------------------------------------------------------------------------
__global__ __launch_bounds__(256) void k2_heads_pairs(
    const float* __restrict__ geo, const float* __restrict__ app,
    const float* __restrict__ con,
    const float* __restrict__ proj,
    const float* __restrict__ w2c, const float* __restrict__ b2c,
    const float* __restrict__ w2r, const float* __restrict__ b2r,
    const float* __restrict__ w2l, const float* __restrict__ b2l,
    float* __restrict__ out, float4* __restrict__ outp)
{
    const int tid = threadIdx.x;
    const int bid = blockIdx.x;

    if (bid >= 200) {
        pairs_chunk(geo, app, con, outp,
                    S1_CHUNKS + (bid - 200) * 256 + tid);
        return;
    }

    __shared__ float P1s[16][516];
    __shared__ float P2s[16][516];
    __shared__ float w2s[1024];
    __shared__ float b2s[2];

    const int b   = bid / 100;           // 10x10 tiles of 16x16 per batch
    const int rem = bid - b * 100;
    const int it  = rem / 10;
    const int jt  = rem - it * 10;
    const int i0 = it * 16, j0 = jt * 16;
    const int ii = tid >> 4, jj = tid & 15;

    #pragma unroll
    for (int t = 0; t < 3; ++t) {
        const float* w2 = (t == 0) ? w2c : ((t == 1) ? w2r : w2l);
        const float* b2 = (t == 0) ? b2c : ((t == 1) ? b2r : b2l);

        // stage P1 (j rows) and P2 (i rows): 2 tiles * 16 rows * 128 float4
        for (int u = tid; u < 4096; u += 256) {
            const int tile = u >> 11;
            const int r    = (u >> 7) & 15;
            const int f4   = u & 127;
            const int p    = b * 160 + (tile ? (i0 + r) : (j0 + r));
            const float4 v = *(const float4*)(
                proj + ((size_t)((t * 2 + tile) * 320 + p)) * 512 + f4 * 4);
            float* dst = tile ? &P2s[r][f4 * 4] : &P1s[r][f4 * 4];
            *(float4*)dst = v;
        }
        *(float4*)&w2s[tid * 4] = *(const float4*)(w2 + tid * 4);
        if (tid < 2) b2s[tid] = b2[tid];
        __syncthreads();

        float a0 = b2s[0], a1 = b2s[1];
        for (int f = 0; f < 512; f += 4) {
            const float4 p1 = *(const float4*)&P1s[jj][f];
            const float4 p2 = *(const float4*)&P2s[ii][f];
            const float4 wA = *(const float4*)&w2s[f * 2];      // f, f+1
            const float4 wB = *(const float4*)&w2s[f * 2 + 4];  // f+2, f+3
            const float h0 = fmaxf(p1.x + p2.x, 0.f);
            const float h1 = fmaxf(p1.y + p2.y, 0.f);
            const float h2 = fmaxf(p1.z + p2.z, 0.f);
            const float h3 = fmaxf(p1.w + p2.w, 0.f);
            a0 += h0 * wA.x + h1 * wA.z + h2 * wB.x + h3 * wB.z;
            a1 += h0 * wA.y + h1 * wA.w + h2 * wB.y + h3 * wB.w;
        }

        const float mx = fmaxf(a0, a1);
        const float e0 = __expf(a0 - mx);
        const float e1 = __expf(a1 - mx);
        const float rs = 1.f / (e0 + e1);

        const int pr = b * 25600 + (i0 + ii) * 160 + (j0 + jj);
        float2 o; o.x = e0 * rs; o.y = e1 * rs;
        ((float2*)out)[t * 51200 + pr] = o;
        __syncthreads();
    }
}

// ---------------------------------------------------------------------------
// K3 (fallback path only): tail pairs chunks — overwrites the in-output proj
// scratch AFTER heads has consumed it.
// ---------------------------------------------------------------------------
__global__ __launch_bounds__(256) void k3_pairs_tail(
    const float* __restrict__ geo, const float* __restrict__ app,
    const float* __restrict__ con, float4* __restrict__ outp)
{
    pairs_chunk(geo, app, con, outp,
                TAIL_START + blockIdx.x * 256 + threadIdx.x);
}

extern "C" void kernel_launch(void* const* d_in, const int* in_sizes, int n_in,
                              void* d_out, int out_size, void* d_ws, size_t ws_size,
                              hipStream_t stream)
{
    const float* geo = (const float*)d_in[0];
    const float* app = (const float*)d_in[1];
    const float* con = (const float*)d_in[2];
    const float* w1c = (const float*)d_in[3];
    const float* b1c = (const float*)d_in[4];
    const float* w2c = (const float*)d_in[5];
    const float* b2c = (const float*)d_in[6];
    const float* w1r = (const float*)d_in[7];
    const float* b1r = (const float*)d_in[8];
    const float* w2r = (const float*)d_in[9];
    const float* b2r = (const float*)d_in[10];
    const float* w1l = (const float*)d_in[11];
    const float* b1l = (const float*)d_in[12];
    const float* w2l = (const float*)d_in[13];
    const float* b2l = (const float*)d_in[14];

    float* out = (float*)d_out;
    float4* outp = (float4*)(out + OUT_PAIRS_OFF);

    // proj scratch: prefer the workspace (removes K3 + its serialization);
    // fall back to the verified output-tail scheme if ws is too small.
    const bool use_ws = (d_ws != nullptr) && (ws_size >= (size_t)PROJ_BYTES);
    float* proj = use_ws ? (float*)d_ws : (out + PROJ_SCRATCH_OFF);

    // 1) proj GEMM (240 blocks) + pairs slice A (55%)
    k1_proj_pairs<<<240 + K1_PAIR_BLOCKS, 256, 0, stream>>>(
        geo, app, con, w1c, w1r, w1l, b1c, b1r, b1l, proj, outp);

    // 2) heads (200 blocks) + pairs slice B (rest, or rest-minus-tail)
    const int k2_pairs = use_ws ? K2_PAIR_BLOCKS_WS : K2_PAIR_BLOCKS_TAIL;
    k2_heads_pairs<<<200 + k2_pairs, 256, 0, stream>>>(
        geo, app, con, proj, w2c, b2c, w2r, b2r, w2l, b2l, out, outp);

    // 3) tail overwrite of in-output scratch (fallback only)
    if (!use_ws)
        k3_pairs_tail<<<960, 256, 0, stream>>>(geo, app, con, outp);
}